// Round 1
// baseline (1307.307 us; speedup 1.0000x reference)
//
#include <hip/hip_runtime.h>

typedef unsigned short ushort_t;
typedef _Float16 half8 __attribute__((ext_vector_type(8)));
typedef float f32x4 __attribute__((ext_vector_type(4)));

constexpr int NN  = 30000;
constexpr int EE  = 480000;
constexpr int HH  = 128;
constexpr int NEXM = 64;

#define MFMA16(a,b,c) __builtin_amdgcn_mfma_f32_16x16x32_f16((a),(b),(c),0,0,0)

__device__ __forceinline__ float fast_tanh(float x){
  // tanh(x) = 1 - 2/(exp2(2x*log2e)+1); exp2/rcp are ~1ulp -> err ~1e-6
  float e2 = __builtin_amdgcn_exp2f(x * 2.885390081777927f);
  return 1.f - 2.f * __builtin_amdgcn_rcpf(e2 + 1.f);
}

// ---------------- weight pre-swizzle into MFMA fragment order -----------------
// layout (ushorts): w1T 3*8192 | w2f 3*16384 | l1f 3*16384 | l2f 3*16384 | bkf 3*16384 | o1f 8192
__global__ __launch_bounds__(256) void prep_weights(
  const float* __restrict__ fw1, const float* __restrict__ fb1,
  const float* __restrict__ fw2, const float* __restrict__ l1w,
  const float* __restrict__ l2w, const float* __restrict__ bw,
  const float* __restrict__ ow1, ushort_t* __restrict__ frags)
{
  int u = blockIdx.x*256 + threadIdx.x;
  float val;
  if (u < 24576){                       // w1T: A-frags of w1^T, K padded 50->64, row50 = bias
    int b = u >> 13; int v = u & 8191;
    int j = v & 7, lane = (v>>3)&63, fid = v>>9;     // fid = mt*2+ks
    int mt = fid>>1, ks = fid&1;
    int f1 = mt*16 + (lane&15);
    int k  = ks*32 + (lane>>4)*8 + j;
    val = (k < 50) ? fw1[(b*50 + k)*128 + f1]
        : (k == 50 ? fb1[b*128 + f1] : 0.f);
  } else {
    int v = u - 24576;
    if (v < 196608){                    // B-frags of 128x128 matrices
      int midx = v >> 14; int v2 = v & 16383;
      int g = midx/3, b = midx - g*3;
      const float* W = (g==0? fw2 : (g==1? l1w : (g==2? l2w : bw))) + b*16384;
      int j = v2&7, lane = (v2>>3)&63, fid = v2>>9;  // fid = ks*8+nt
      int ks = fid>>3, nt = fid&7;
      int k   = ks*32 + (lane>>4)*8 + j;
      int col = nt*16 + (lane&15);
      val = W[k*128 + col];
    } else {                            // out_w1 [128x64] B-frags, fid = ks*4+nt
      int v3 = v - 196608;
      int j = v3&7, lane=(v3>>3)&63, fid=v3>>9;
      int ks = fid>>2, nt = fid&3;
      int k   = ks*32 + (lane>>4)*8 + j;
      int col = nt*16 + (lane&15);
      val = ow1[k*64 + col];
    }
  }
  union { _Float16 h; ushort_t s; } cv; cv.h = (_Float16)val;
  frags[u] = cv.s;
}

// ---------------- edge geometry: d -> C, rbf (fp16, padded K=64, rbf[50]=1) ----
__global__ __launch_bounds__(256) void edge_prep(
  const float* __restrict__ pos, const int* __restrict__ ei,
  ushort_t* __restrict__ rbf, float* __restrict__ C)
{
  __shared__ float sd[64];
  int tid = threadIdx.x;
  int e0 = blockIdx.x*64;
  if (tid < 64){
    int e = e0 + tid;
    int s = ei[e], d = ei[EE + e];
    float dx = pos[s*3+0]-pos[d*3+0];
    float dy = pos[s*3+1]-pos[d*3+1];
    float dz = pos[s*3+2]-pos[d*3+2];
    float dist = sqrtf(dx*dx+dy*dy+dz*dz + 1e-12f);
    sd[tid] = dist;
    float c = 0.5f*(cosf(dist*0.31415926535897931f)+1.f);
    C[e] = (dist < 10.f) ? c : 0.f;
  }
  __syncthreads();
  int el = tid>>2, part = tid&3;
  float dist = sd[el];
  const float dd = 10.f/49.f;
  const float coefl2 = (-0.5f/(dd*dd)) * 1.4426950408889634f;  // coeff*log2(e)
  union { ushort_t s[16]; uint4 q[2]; } ov;
  #pragma unroll
  for (int i=0;i<16;i++){
    int k = part*16 + i;
    float v;
    if (k < 50){ float t = dist - (float)k*dd; v = __builtin_amdgcn_exp2f(coefl2*t*t); }
    else v = (k==50) ? 1.f : 0.f;
    union { _Float16 h; ushort_t s; } cv; cv.h = (_Float16)v;
    ov.s[i] = cv.s;
  }
  uint4* dst = (uint4*)(rbf + (size_t)(e0+el)*64 + part*16);
  dst[0] = ov.q[0];
  dst[1] = ov.q[1];
}

// ---------------- embedding gather -------------------------------------------
__global__ __launch_bounds__(256) void embed_kernel(
  const int* __restrict__ atype, const float* __restrict__ emb, float* __restrict__ x)
{
  int id = blockIdx.x*256 + threadIdx.x;
  int a = id >> 7, f = id & 127;
  x[id] = emb[atype[a]*128 + f];
}

// ---------------- fused filter net + message + scatter ------------------------
__global__ __launch_bounds__(256,1) void filter_msg(
  const ushort_t* __restrict__ rbf, const float* __restrict__ C,
  const ushort_t* __restrict__ h, const int* __restrict__ src, const int* __restrict__ dst,
  const ushort_t* __restrict__ w1T, const ushort_t* __restrict__ w2f,
  const float* __restrict__ b2, float* __restrict__ agg)
{
  __shared__ ushort_t st[4*16*132];
  const int wave = threadIdx.x>>6, lane = threadIdx.x&63;
  const int quad = lane>>4, n15 = lane&15;
  ushort_t* tw = st + wave*16*132;

  // persistent weight fragments in VGPRs
  half8 a1[16];
  const half8* w1v = (const half8*)w1T;
  #pragma unroll
  for (int i=0;i<16;i++) a1[i] = w1v[i*64 + lane];
  half8 b2f[32];
  const half8* w2v = (const half8*)w2f;
  #pragma unroll
  for (int i=0;i<32;i++) b2f[i] = w2v[i*64 + lane];
  float bias2[8];
  #pragma unroll
  for (int nt=0;nt<8;nt++) bias2[nt] = b2[nt*16 + n15];

  const f32x4 zero4 = {0.f,0.f,0.f,0.f};
  int stride = gridDim.x*4;
  for (int tile = blockIdx.x*4 + wave; tile < EE/16; tile += stride){
    int e0 = tile*16;
    // B-frags of rbf (row = n15, k contiguous) straight from global
    const half8* rv = (const half8*)(rbf + (size_t)e0*64);
    half8 rb0 = rv[n15*8 + quad];
    half8 rb1 = rv[n15*8 + 4 + quad];
    // GEMM1: D1[f1, e] (bias folded via k=50 row)
    f32x4 acc1[8];
    #pragma unroll
    for (int mt=0;mt<8;mt++){
      acc1[mt] = MFMA16(a1[mt*2],   rb0, zero4);
      acc1[mt] = MFMA16(a1[mt*2+1], rb1, acc1[mt]);
    }
    // tanh + fp16 pack (RTN) + LDS store: t[e=n15][f1 = mt*16+quad*4+r]
    #pragma unroll
    for (int mt=0;mt<8;mt++){
      union { ushort_t s[4]; uint2 v; } pk;
      #pragma unroll
      for (int r=0;r<4;r++){
        union { _Float16 h16; ushort_t s; } cv;
        cv.h16 = (_Float16)fast_tanh(acc1[mt][r]);
        pk.s[r] = cv.s;
      }
      *(uint2*)(tw + n15*132 + mt*16 + quad*4) = pk.v;
    }
    asm volatile("s_waitcnt lgkmcnt(0)" ::: "memory");
    // GEMM2: A = t from LDS (m=e), B = w2 frags (n=f2)
    f32x4 acc2[8];
    #pragma unroll
    for (int nt=0;nt<8;nt++) acc2[nt] = zero4;
    #pragma unroll
    for (int ks=0;ks<4;ks++){
      const ushort_t* ra = tw + n15*132 + ks*32 + quad*8;
      union { uint2 v[2]; half8 h16; } cc;
      cc.v[0] = *(const uint2*)(ra);
      cc.v[1] = *(const uint2*)(ra + 4);
      half8 a2 = cc.h16;
      #pragma unroll
      for (int nt=0;nt<8;nt++) acc2[nt] = MFMA16(a2, b2f[ks*8+nt], acc2[nt]);
    }
    // epilogue: W = (acc2 + b2)*C[e]; msg = h[src]*W; atomic scatter to agg[dst]
    float Cv[4]; int sv[4], dv[4];
    #pragma unroll
    for (int r=0;r<4;r++){
      int e = e0 + quad*4 + r;
      Cv[r] = C[e]; sv[r] = src[e]; dv[r] = dst[e];
    }
    #pragma unroll
    for (int nt=0;nt<8;nt++){
      #pragma unroll
      for (int r=0;r<4;r++){
        float Wv = (acc2[nt][r] + bias2[nt]) * Cv[r];
        float hv = (float)(*(const _Float16*)(h + (size_t)sv[r]*128 + nt*16 + n15));
        __hip_atomic_fetch_add(agg + (size_t)dv[r]*128 + nt*16 + n15, hv*Wv,
                               __ATOMIC_RELAXED, __HIP_MEMORY_SCOPE_AGENT);
      }
    }
  }
}

// ---------------- node GEMM: out_f16[N, NT*16] = [tanh](in_f32 @ W + bias) ----
template<int NT>
__global__ __launch_bounds__(256,1) void node_gemm(
  const float* __restrict__ in, const ushort_t* __restrict__ bfrag,
  const float* __restrict__ bias, int do_tanh, ushort_t* __restrict__ out)
{
  const int wave = threadIdx.x>>6, lane = threadIdx.x&63;
  const int quad = lane>>4, n15 = lane&15;
  half8 bf[NT*4];
  const half8* bv = (const half8*)bfrag;
  #pragma unroll
  for (int i=0;i<NT*4;i++) bf[i] = bv[i*64 + lane];
  float brg[NT];
  #pragma unroll
  for (int nt=0;nt<NT;nt++) brg[nt] = bias ? bias[nt*16 + n15] : 0.f;

  const f32x4 zero4 = {0.f,0.f,0.f,0.f};
  int stride = gridDim.x*4;
  for (int tile = blockIdx.x*4 + wave; tile < NN/16; tile += stride){
    int a0 = tile*16;
    const f32x4* inv = (const f32x4*)(in + (size_t)(a0 + n15)*128);
    half8 af[4];
    #pragma unroll
    for (int ks=0;ks<4;ks++){
      f32x4 lo = inv[ks*8 + quad*2];
      f32x4 hi = inv[ks*8 + quad*2 + 1];
      half8 ah;
      #pragma unroll
      for (int i=0;i<4;i++){ ah[i] = (_Float16)lo[i]; ah[4+i] = (_Float16)hi[i]; }
      af[ks] = ah;
    }
    f32x4 acc[NT];
    #pragma unroll
    for (int nt=0;nt<NT;nt++) acc[nt] = zero4;
    #pragma unroll
    for (int ks=0;ks<4;ks++){
      #pragma unroll
      for (int nt=0;nt<NT;nt++) acc[nt] = MFMA16(af[ks], bf[ks*NT+nt], acc[nt]);
    }
    #pragma unroll
    for (int nt=0;nt<NT;nt++){
      #pragma unroll
      for (int r=0;r<4;r++){
        float v = acc[nt][r] + brg[nt];
        if (do_tanh) v = fast_tanh(v);
        union { _Float16 h16; ushort_t s; } cv; cv.h16 = (_Float16)v;
        out[(size_t)(a0 + quad*4 + r)*(NT*16) + nt*16 + n15] = cv.s;
      }
    }
  }
}

// ---------------- node residual: x_f32 += t1_f16 @ W + bias -------------------
__global__ __launch_bounds__(256,1) void node_res(
  const ushort_t* __restrict__ t1, const ushort_t* __restrict__ bfrag,
  const float* __restrict__ bias, float* __restrict__ x)
{
  const int wave = threadIdx.x>>6, lane = threadIdx.x&63;
  const int quad = lane>>4, n15 = lane&15;
  half8 bf[32];
  const half8* bv = (const half8*)bfrag;
  #pragma unroll
  for (int i=0;i<32;i++) bf[i] = bv[i*64 + lane];
  float brg[8];
  #pragma unroll
  for (int nt=0;nt<8;nt++) brg[nt] = bias[nt*16 + n15];

  const f32x4 zero4 = {0.f,0.f,0.f,0.f};
  int stride = gridDim.x*4;
  for (int tile = blockIdx.x*4 + wave; tile < NN/16; tile += stride){
    int a0 = tile*16;
    const half8* inv = (const half8*)(t1 + (size_t)(a0 + n15)*128);
    half8 af[4];
    #pragma unroll
    for (int ks=0;ks<4;ks++) af[ks] = inv[ks*4 + quad];
    f32x4 acc[8];
    #pragma unroll
    for (int nt=0;nt<8;nt++) acc[nt] = zero4;
    #pragma unroll
    for (int ks=0;ks<4;ks++){
      #pragma unroll
      for (int nt=0;nt<8;nt++) acc[nt] = MFMA16(af[ks], bf[ks*8+nt], acc[nt]);
    }
    #pragma unroll
    for (int nt=0;nt<8;nt++){
      #pragma unroll
      for (int r=0;r<4;r++){
        size_t idx = (size_t)(a0 + quad*4 + r)*128 + nt*16 + n15;
        x[idx] = x[idx] + acc[nt][r] + brg[nt];
      }
    }
  }
}

// ---------------- output head stage 2 + per-molecule reduce -------------------
__global__ __launch_bounds__(256) void out_final(
  const ushort_t* __restrict__ tout, const float* __restrict__ ow2,
  const float* __restrict__ ob2, const int* __restrict__ batch, float* __restrict__ out)
{
  __shared__ float part[NEXM];
  int tid = threadIdx.x;
  if (tid < NEXM) part[tid] = 0.f;
  __syncthreads();
  int a = blockIdx.x*256 + tid;
  if (a < NN){
    float e = 0.f;
    const half8* tv = (const half8*)(tout + (size_t)a*64);
    #pragma unroll
    for (int c=0;c<8;c++){
      half8 v = tv[c];
      #pragma unroll
      for (int i=0;i<8;i++) e += (float)v[i] * ow2[c*8+i];
    }
    e += ob2[0];
    __hip_atomic_fetch_add(&part[batch[a]], e, __ATOMIC_RELAXED, __HIP_MEMORY_SCOPE_WORKGROUP);
  }
  __syncthreads();
  if (tid < NEXM)
    __hip_atomic_fetch_add(out + tid, part[tid], __ATOMIC_RELAXED, __HIP_MEMORY_SCOPE_AGENT);
}

// ---------------- host orchestration ------------------------------------------
extern "C" void kernel_launch(void* const* d_in, const int* in_sizes, int n_in,
                              void* d_out, int out_size, void* d_ws, size_t ws_size,
                              hipStream_t stream)
{
  const float* pos  = (const float*)d_in[0];
  const int*   atyp = (const int*)  d_in[1];
  const int*   ei   = (const int*)  d_in[2];
  const int*   bat  = (const int*)  d_in[3];
  const float* emb  = (const float*)d_in[4];
  const float* fw1  = (const float*)d_in[5];
  const float* fb1  = (const float*)d_in[6];
  const float* fw2  = (const float*)d_in[7];
  const float* fb2  = (const float*)d_in[8];
  const float* l1w  = (const float*)d_in[9];
  const float* l2w  = (const float*)d_in[10];
  const float* l2b  = (const float*)d_in[11];
  const float* bw   = (const float*)d_in[12];
  const float* bb   = (const float*)d_in[13];
  const float* ow1  = (const float*)d_in[14];
  const float* ob1  = (const float*)d_in[15];
  const float* ow2  = (const float*)d_in[16];
  const float* ob2  = (const float*)d_in[17];
  float* out = (float*)d_out;

  char* p = (char*)d_ws;
  ushort_t* rbf = (ushort_t*)p; p += (size_t)EE*64*2;   // 61.44 MB
  float*    C   = (float*)p;    p += (size_t)EE*4;      // 1.92 MB
  ushort_t* h   = (ushort_t*)p; p += (size_t)NN*128*2;  // 7.68 MB
  float*    x   = (float*)p;    p += (size_t)NN*128*4;  // 15.36 MB
  float*    agg = (float*)p;    p += (size_t)NN*128*4;  // 15.36 MB
  ushort_t* t1  = (ushort_t*)p; p += (size_t)NN*128*2;  // 7.68 MB (reused as t_out)
  ushort_t* frags = (ushort_t*)p;                       // 458752 B

  ushort_t* w1T = frags;
  ushort_t* w2f = frags + 24576;
  ushort_t* l1f = frags + 73728;
  ushort_t* l2f = frags + 122880;
  ushort_t* bkf = frags + 172032;
  ushort_t* o1f = frags + 221184;

  hipMemsetAsync(d_out, 0, NEXM*sizeof(float), stream);
  prep_weights<<<896,256,0,stream>>>(fw1,fb1,fw2,l1w,l2w,bw,ow1,frags);
  edge_prep<<<EE/64,256,0,stream>>>(pos, ei, rbf, C);
  embed_kernel<<<(NN*128)/256,256,0,stream>>>(atyp, emb, x);
  node_gemm<8><<<256,256,0,stream>>>(x, l1f, nullptr, 0, h);   // h = x @ lin1[0]

  for (int b=0;b<3;b++){
    hipMemsetAsync(agg, 0, (size_t)NN*128*4, stream);
    filter_msg<<<256,256,0,stream>>>(rbf, C, h, ei, ei+EE,
                                     w1T + b*8192, w2f + b*16384, fb2 + b*128, agg);
    node_gemm<8><<<256,256,0,stream>>>(agg, l2f + b*16384, l2b + b*128, 1, t1); // t1 = tanh(agg@lin2+b)
    node_res<<<256,256,0,stream>>>(t1, bkf + b*16384, bb + b*128, x);           // x += t1@blk + bb
    if (b < 2)
      node_gemm<8><<<256,256,0,stream>>>(x, l1f + (b+1)*16384, nullptr, 0, h);  // h = x @ lin1[b+1]
  }
  node_gemm<4><<<256,256,0,stream>>>(x, o1f, ob1, 1, t1);       // t_out = tanh(x@ow1+b1)
  out_final<<<(NN+255)/256,256,0,stream>>>(t1, ow2, ob2, bat, out);
}